// Round 4
// baseline (1231.696 us; speedup 1.0000x reference)
//
#include <hip/hip_runtime.h>

#define EDGES 200000
#define NATOMS 100000
#define NMOLS 2000
#define H 128
#define MAXNB 15
#define AFD 18
#define INFD 23
#define LROW 136  // LDS A-tile row stride in bf16 units (+8 pad: 2-way banks, 16B aligned)

typedef unsigned short bf16s;
typedef __attribute__((ext_vector_type(8))) short short8;
typedef __attribute__((ext_vector_type(4))) float f32x4;

__device__ inline float bf2f(bf16s u) {
  union { unsigned int i; float f; } c; c.i = ((unsigned int)u) << 16; return c.f;
}
__device__ inline bf16s f2bf(float f) {
  union { float f; unsigned int i; } c; c.f = f;
  unsigned int lsb = (c.i >> 16) & 1u;
  c.i += 0x7fffu + lsb;              // round-to-nearest-even
  return (bf16s)(c.i >> 16);
}
__device__ inline void load4(const bf16s* p, float v[4]) {
  ushort4 t = *(const ushort4*)p;
  v[0] = bf2f(t.x); v[1] = bf2f(t.y); v[2] = bf2f(t.z); v[3] = bf2f(t.w);
}
__device__ inline void store4(bf16s* p, const float v[4]) {
  ushort4 t; t.x = f2bf(v[0]); t.y = f2bf(v[1]); t.z = f2bf(v[2]); t.w = f2bf(v[3]);
  *(ushort4*)p = t;
}

// ------- one-time: Wt[n][k] = bf16(W[k][n]) for W_h and W_o[AFD:,:] -------
__global__ __launch_bounds__(256) void k_wt(
    const float* __restrict__ Wh, const float* __restrict__ Wo,
    bf16s* __restrict__ wt_h, bf16s* __restrict__ wt_o) {
  const float* S = blockIdx.x ? (Wo + AFD * H) : Wh;
  bf16s* D = blockIdx.x ? wt_o : wt_h;
  for (int i = threadIdx.x; i < H * H; i += 256) {
    int k = i >> 7, n = i & 127;
    D[n * H + k] = f2bf(S[i]);
  }
}

// MFMA phase: A-tile (64x128 bf16, LDS, stride LROW) @ Wt -> C[row0..row0+63]
// A-frag: A[m=lane&15][k=quad*8+j]; B-frag from Wt[n][k] rows; D row=quad*4+i.
__device__ inline void mfma_tile_store(const bf16s* Am, const bf16s* __restrict__ Wt,
                                       bf16s* __restrict__ C, int row0) {
  const int wave = threadIdx.x >> 6;
  const int lane = threadIdx.x & 63;
  const int m = lane & 15;
  const int quad = lane >> 4;
  f32x4 acc[8];
#pragma unroll
  for (int i = 0; i < 8; ++i) acc[i] = (f32x4){0.f, 0.f, 0.f, 0.f};
  const bf16s* Ap = Am + (wave * 16 + m) * LROW + quad * 8;
  const bf16s* Wp = Wt + (size_t)m * H + quad * 8;
#pragma unroll
  for (int kk = 0; kk < 4; ++kk) {
    short8 af = *(const short8*)(Ap + kk * 32);
#pragma unroll
    for (int nt = 0; nt < 8; ++nt) {
      short8 bfr = *(const short8*)(Wp + (size_t)(nt * 16) * H + kk * 32);
      acc[nt] = __builtin_amdgcn_mfma_f32_16x16x32_bf16(af, bfr, acc[nt], 0, 0, 0);
    }
  }
  const int rbase = row0 + wave * 16 + quad * 4;
#pragma unroll
  for (int nt = 0; nt < 8; ++nt) {
#pragma unroll
    for (int i = 0; i < 4; ++i) {
      C[(size_t)(rbase + i) * H + nt * 16 + m] = f2bf(acc[nt][i]);
    }
  }
}

// ---- binput = fbonds @ W_i (stored); P0 = relu(binput) @ W_h (fused MFMA) ----
__global__ __launch_bounds__(256) void k_binput_fused(
    const float* __restrict__ fbonds, const float* __restrict__ Wi,
    const bf16s* __restrict__ wt_h, bf16s* __restrict__ binput,
    bf16s* __restrict__ P0) {
  __shared__ float Wl[INFD * H];
  __shared__ bf16s Am[64 * LROW];
  const int tid = threadIdx.x;
  for (int i = tid; i < INFD * H; i += 256) Wl[i] = Wi[i];
  __syncthreads();
  const int g = tid >> 5;
  const int lane32 = tid & 31;
  const int ebase = blockIdx.x * 64 + g * 8;
  for (int j = 0; j < 8; ++j) {
    const int e = ebase + j;
    const float* fb = &fbonds[(size_t)e * INFD];
    float acc[4] = {0.f, 0.f, 0.f, 0.f};
#pragma unroll
    for (int k = 0; k < INFD; ++k) {
      float f = fb[k];
      float4 w = *(const float4*)&Wl[k * H + lane32 * 4];
      acc[0] = fmaf(f, w.x, acc[0]); acc[1] = fmaf(f, w.y, acc[1]);
      acc[2] = fmaf(f, w.z, acc[2]); acc[3] = fmaf(f, w.w, acc[3]);
    }
    store4(&binput[(size_t)e * H + lane32 * 4], acc);
    float r[4] = {fmaxf(acc[0], 0.f), fmaxf(acc[1], 0.f),
                  fmaxf(acc[2], 0.f), fmaxf(acc[3], 0.f)};
    store4(&Am[(g * 8 + j) * LROW + lane32 * 4], r);
  }
  __syncthreads();
  mfma_tile_store(Am, wt_h, P0, blockIdx.x * 64);
}

// ---- fused depth step: Pout = (relu(binput + sum_j P[bgraph[e][j]])) @ Wt ----
__global__ __launch_bounds__(256) void k_fused_mp(
    const int* __restrict__ bgraph, const bf16s* __restrict__ P,
    const bf16s* __restrict__ binput, const bf16s* __restrict__ Wt,
    bf16s* __restrict__ Pout) {
  __shared__ bf16s Am[64 * LROW];
  const int tid = threadIdx.x;
  const int g = tid >> 5;
  const int lane32 = tid & 31;
  const int ebase = blockIdx.x * 64 + g * 8;
  // two edges per iteration for memory-level parallelism (30 loads in flight)
  for (int j2 = 0; j2 < 4; ++j2) {
    const int e0 = ebase + j2 * 2;
    const int e1 = e0 + 1;
    int idx0[MAXNB], idx1[MAXNB];
#pragma unroll
    for (int j = 0; j < MAXNB; ++j) idx0[j] = bgraph[(size_t)e0 * MAXNB + j];
#pragma unroll
    for (int j = 0; j < MAXNB; ++j) idx1[j] = bgraph[(size_t)e1 * MAXNB + j];
    float a0[4], a1[4];
    load4(&binput[(size_t)e0 * H + lane32 * 4], a0);
    load4(&binput[(size_t)e1 * H + lane32 * 4], a1);
#pragma unroll
    for (int j = 0; j < MAXNB; ++j) {
      float t[4];
      load4(&P[(size_t)idx0[j] * H + lane32 * 4], t);
      a0[0] += t[0]; a0[1] += t[1]; a0[2] += t[2]; a0[3] += t[3];
    }
#pragma unroll
    for (int j = 0; j < MAXNB; ++j) {
      float t[4];
      load4(&P[(size_t)idx1[j] * H + lane32 * 4], t);
      a1[0] += t[0]; a1[1] += t[1]; a1[2] += t[2]; a1[3] += t[3];
    }
#pragma unroll
    for (int i = 0; i < 4; ++i) { a0[i] = fmaxf(a0[i], 0.f); a1[i] = fmaxf(a1[i], 0.f); }
    store4(&Am[(g * 8 + j2 * 2) * LROW + lane32 * 4], a0);
    store4(&Am[(g * 8 + j2 * 2 + 1) * LROW + lane32 * 4], a1);
  }
  __syncthreads();
  mfma_tile_store(Am, Wt, Pout, blockIdx.x * 64);
}

// atom_hiddens = relu(fatoms @ Wo[0:18] + sum_j msgWo[agraph[a][j]] + b_o)
__global__ __launch_bounds__(256) void k_atoms(
    const float* __restrict__ fatoms, const int* __restrict__ agraph,
    const bf16s* __restrict__ msgWo, const float* __restrict__ Wo,
    const float* __restrict__ bo, float* __restrict__ atomh) {
  __shared__ float Wl[AFD * H];
  const int tid = threadIdx.x;
  for (int i = tid; i < AFD * H; i += 256) Wl[i] = Wo[i];
  __syncthreads();
  const int lane = tid & 31;
  const int a = blockIdx.x * 8 + (tid >> 5);
  float4 b = ((const float4*)bo)[lane];
  float acc[4] = {b.x, b.y, b.z, b.w};
#pragma unroll
  for (int k = 0; k < AFD; ++k) {
    float f = fatoms[(size_t)a * AFD + k];
    float4 w = *(const float4*)&Wl[k * H + lane * 4];
    acc[0] = fmaf(f, w.x, acc[0]); acc[1] = fmaf(f, w.y, acc[1]);
    acc[2] = fmaf(f, w.z, acc[2]); acc[3] = fmaf(f, w.w, acc[3]);
  }
  int idx[MAXNB];
#pragma unroll
  for (int j = 0; j < MAXNB; ++j) idx[j] = agraph[(size_t)a * MAXNB + j];
#pragma unroll
  for (int j = 0; j < MAXNB; ++j) {
    float t[4];
    load4(&msgWo[(size_t)idx[j] * H + lane * 4], t);
    acc[0] += t[0]; acc[1] += t[1]; acc[2] += t[2]; acc[3] += t[3];
  }
  float r[4] = {fmaxf(acc[0], 0.f), fmaxf(acc[1], 0.f),
                fmaxf(acc[2], 0.f), fmaxf(acc[3], 0.f)};
  *(float4*)&atomh[(size_t)a * H + lane * 4] = make_float4(r[0], r[1], r[2], r[3]);
}

// ---------------- segment mean pool ----------------
__global__ void k_pool(const float* __restrict__ atomh,
                       const int* __restrict__ sstart, const int* __restrict__ slen,
                       float* __restrict__ out) {
  const int m = blockIdx.x;
  const int c = threadIdx.x;
  const int s = sstart[m];
  const int L = slen[m];
  float sum = 0.f;
  for (int i = 0; i < L; ++i) sum += atomh[(size_t)(s + i) * H + c];
  out[m * H + c] = sum / (float)L;
}

extern "C" void kernel_launch(void* const* d_in, const int* in_sizes, int n_in,
                              void* d_out, int out_size, void* d_ws, size_t ws_size,
                              hipStream_t stream) {
  const float* fatoms = (const float*)d_in[0];
  const float* fbonds = (const float*)d_in[1];
  const int* agraph = (const int*)d_in[2];
  const int* bgraph = (const int*)d_in[3];
  const int* sstart = (const int*)d_in[4];
  const int* slen = (const int*)d_in[5];
  const float* Wi = (const float*)d_in[6];
  const float* Wh = (const float*)d_in[7];
  const float* Wo = (const float*)d_in[8];
  const float* bo = (const float*)d_in[9];
  float* out = (float*)d_out;

  const size_t EH = (size_t)EDGES * H;
  bf16s* B0 = (bf16s*)d_ws;      // binput [E,H] bf16
  bf16s* B1 = B0 + EH;           // ping
  bf16s* B2 = B1 + EH;           // pong
  // bf16 transposed weights stashed in d_out; k_pool fully overwrites it later
  bf16s* wt_h = (bf16s*)d_out;
  bf16s* wt_o = wt_h + H * H;

  k_wt<<<2, 256, 0, stream>>>(Wh, Wo, wt_h, wt_o);
  k_binput_fused<<<EDGES / 64, 256, 0, stream>>>(fbonds, Wi, wt_h, B0, B1);
  // 4 hidden steps: B1->B2->B1->B2->B1 ; final (Wo) step: B1->B2
  k_fused_mp<<<EDGES / 64, 256, 0, stream>>>(bgraph, B1, B0, wt_h, B2);
  k_fused_mp<<<EDGES / 64, 256, 0, stream>>>(bgraph, B2, B0, wt_h, B1);
  k_fused_mp<<<EDGES / 64, 256, 0, stream>>>(bgraph, B1, B0, wt_h, B2);
  k_fused_mp<<<EDGES / 64, 256, 0, stream>>>(bgraph, B2, B0, wt_h, B1);
  k_fused_mp<<<EDGES / 64, 256, 0, stream>>>(bgraph, B1, B0, wt_o, B2);
  float* atomh = (float*)B1;     // [N,H] fp32 = 51.2 MB, overlays dead ping buffer
  k_atoms<<<NATOMS / 8, 256, 0, stream>>>(fatoms, agraph, B2, Wo, bo, atomh);
  k_pool<<<NMOLS, H, 0, stream>>>(atomh, sstart, slen, out);
}

// Round 5
// 1142.537 us; speedup vs baseline: 1.0780x; 1.0780x over previous
//
#include <hip/hip_runtime.h>

#define EDGES 200000
#define NATOMS 100000
#define NMOLS 2000
#define H 128
#define MAXNB 15
#define AFD 18
#define INFD 23

typedef unsigned short bf16s;
typedef __attribute__((ext_vector_type(8))) short short8;
typedef __attribute__((ext_vector_type(4))) float f32x4;

__device__ inline float bf2f(bf16s u) {
  union { unsigned int i; float f; } c; c.i = ((unsigned int)u) << 16; return c.f;
}
__device__ inline bf16s f2bf(float f) {
  union { float f; unsigned int i; } c; c.f = f;
  unsigned int lsb = (c.i >> 16) & 1u;
  c.i += 0x7fffu + lsb;              // round-to-nearest-even
  return (bf16s)(c.i >> 16);
}
__device__ inline void load4(const bf16s* p, float v[4]) {
  ushort4 t = *(const ushort4*)p;
  v[0] = bf2f(t.x); v[1] = bf2f(t.y); v[2] = bf2f(t.z); v[3] = bf2f(t.w);
}
__device__ inline void store4(bf16s* p, const float v[4]) {
  ushort4 t; t.x = f2bf(v[0]); t.y = f2bf(v[1]); t.z = f2bf(v[2]); t.w = f2bf(v[3]);
  *(ushort4*)p = t;
}

// ------- one-time: Wt[n][k] = bf16(W[k][n]) for W_h and W_o[AFD:,:] -------
__global__ __launch_bounds__(256) void k_wt(
    const float* __restrict__ Wh, const float* __restrict__ Wo,
    bf16s* __restrict__ wt_h, bf16s* __restrict__ wt_o) {
  const float* S = blockIdx.x ? (Wo + AFD * H) : Wh;
  bf16s* D = blockIdx.x ? wt_o : wt_h;
  for (int i = threadIdx.x; i < H * H; i += 256) {
    int k = i >> 7, n = i & 127;
    D[n * H + k] = f2bf(S[i]);
  }
}

// ---------------- binput = fbonds @ W_i ; message = relu(binput) ----------------
__global__ __launch_bounds__(256) void k_binput(
    const float* __restrict__ fbonds, const float* __restrict__ Wi,
    bf16s* __restrict__ binput, bf16s* __restrict__ message) {
  __shared__ float Wl[INFD * H];
  const int tid = threadIdx.x;
  for (int i = tid; i < INFD * H; i += 256) Wl[i] = Wi[i];
  __syncthreads();
  const int lane = tid & 31;
  const int e = blockIdx.x * 8 + (tid >> 5);
  const float* fb = &fbonds[(size_t)e * INFD];
  float acc[4] = {0.f, 0.f, 0.f, 0.f};
#pragma unroll
  for (int k = 0; k < INFD; ++k) {
    float f = fb[k];
    float4 w = *(const float4*)&Wl[k * H + lane * 4];
    acc[0] = fmaf(f, w.x, acc[0]); acc[1] = fmaf(f, w.y, acc[1]);
    acc[2] = fmaf(f, w.z, acc[2]); acc[3] = fmaf(f, w.w, acc[3]);
  }
  store4(&binput[(size_t)e * H + lane * 4], acc);
  float r[4] = {fmaxf(acc[0], 0.f), fmaxf(acc[1], 0.f),
                fmaxf(acc[2], 0.f), fmaxf(acc[3], 0.f)};
  store4(&message[(size_t)e * H + lane * 4], r);
}

// ---------------- C[E,128] = A[E,128] @ W, MFMA bf16, no LDS ----------------
__global__ __launch_bounds__(256) void k_gemm_mfma(
    const bf16s* __restrict__ A, const bf16s* __restrict__ Wt,
    bf16s* __restrict__ C) {
  const int wave = threadIdx.x >> 6;
  const int lane = threadIdx.x & 63;
  const int m = lane & 15;
  const int quad = lane >> 4;
  const int row0 = blockIdx.x * 64 + wave * 16;

  f32x4 acc[8];
#pragma unroll
  for (int i = 0; i < 8; ++i) acc[i] = (f32x4){0.f, 0.f, 0.f, 0.f};

  const bf16s* Ap = A + (size_t)(row0 + m) * H + quad * 8;
  const bf16s* Wp = Wt + (size_t)m * H + quad * 8;

#pragma unroll
  for (int kk = 0; kk < 4; ++kk) {
    short8 af = *(const short8*)(Ap + kk * 32);
#pragma unroll
    for (int nt = 0; nt < 8; ++nt) {
      short8 bfr = *(const short8*)(Wp + (size_t)(nt * 16) * H + kk * 32);
      acc[nt] = __builtin_amdgcn_mfma_f32_16x16x32_bf16(af, bfr, acc[nt], 0, 0, 0);
    }
  }
  const int rbase = row0 + quad * 4;
#pragma unroll
  for (int nt = 0; nt < 8; ++nt) {
#pragma unroll
    for (int i = 0; i < 4; ++i) {
      C[(size_t)(rbase + i) * H + nt * 16 + m] = f2bf(acc[nt][i]);
    }
  }
}

// ------------- message' = relu(binput + sum_j msgW[bgraph[e][j]]) -------------
// All 15 row loads buffered in registers (30 VGPRs payload) so they issue
// back-to-back: 15 outstanding global loads per 32-lane group.
__global__ __launch_bounds__(256) void k_gather_relu(
    const int* __restrict__ bgraph, const bf16s* __restrict__ msgW,
    const bf16s* __restrict__ binput, bf16s* __restrict__ out) {
  const int tid = threadIdx.x;
  const int lane = tid & 31;
  const int e = blockIdx.x * 8 + (tid >> 5);
  int idx[MAXNB];
#pragma unroll
  for (int j = 0; j < MAXNB; ++j) idx[j] = bgraph[(size_t)e * MAXNB + j];
  ushort4 t[MAXNB];
#pragma unroll
  for (int j = 0; j < MAXNB; ++j)
    t[j] = *(const ushort4*)&msgW[(size_t)idx[j] * H + lane * 4];
  float acc[4];
  load4(&binput[(size_t)e * H + lane * 4], acc);
#pragma unroll
  for (int j = 0; j < MAXNB; ++j) {
    acc[0] += bf2f(t[j].x); acc[1] += bf2f(t[j].y);
    acc[2] += bf2f(t[j].z); acc[3] += bf2f(t[j].w);
  }
  acc[0] = fmaxf(acc[0], 0.f); acc[1] = fmaxf(acc[1], 0.f);
  acc[2] = fmaxf(acc[2], 0.f); acc[3] = fmaxf(acc[3], 0.f);
  store4(&out[(size_t)e * H + lane * 4], acc);
}

// atom_hiddens = relu(fatoms @ Wo[0:18] + sum_j msgWo[agraph[a][j]] + b_o)
__global__ __launch_bounds__(256) void k_atoms(
    const float* __restrict__ fatoms, const int* __restrict__ agraph,
    const bf16s* __restrict__ msgWo, const float* __restrict__ Wo,
    const float* __restrict__ bo, float* __restrict__ atomh) {
  __shared__ float Wl[AFD * H];
  const int tid = threadIdx.x;
  for (int i = tid; i < AFD * H; i += 256) Wl[i] = Wo[i];
  __syncthreads();
  const int lane = tid & 31;
  const int a = blockIdx.x * 8 + (tid >> 5);
  int idx[MAXNB];
#pragma unroll
  for (int j = 0; j < MAXNB; ++j) idx[j] = agraph[(size_t)a * MAXNB + j];
  ushort4 t[MAXNB];
#pragma unroll
  for (int j = 0; j < MAXNB; ++j)
    t[j] = *(const ushort4*)&msgWo[(size_t)idx[j] * H + lane * 4];
  float4 b = ((const float4*)bo)[lane];
  float acc[4] = {b.x, b.y, b.z, b.w};
#pragma unroll
  for (int k = 0; k < AFD; ++k) {
    float f = fatoms[(size_t)a * AFD + k];
    float4 w = *(const float4*)&Wl[k * H + lane * 4];
    acc[0] = fmaf(f, w.x, acc[0]); acc[1] = fmaf(f, w.y, acc[1]);
    acc[2] = fmaf(f, w.z, acc[2]); acc[3] = fmaf(f, w.w, acc[3]);
  }
#pragma unroll
  for (int j = 0; j < MAXNB; ++j) {
    acc[0] += bf2f(t[j].x); acc[1] += bf2f(t[j].y);
    acc[2] += bf2f(t[j].z); acc[3] += bf2f(t[j].w);
  }
  float r[4] = {fmaxf(acc[0], 0.f), fmaxf(acc[1], 0.f),
                fmaxf(acc[2], 0.f), fmaxf(acc[3], 0.f)};
  *(float4*)&atomh[(size_t)a * H + lane * 4] = make_float4(r[0], r[1], r[2], r[3]);
}

// ---------------- segment mean pool ----------------
__global__ void k_pool(const float* __restrict__ atomh,
                       const int* __restrict__ sstart, const int* __restrict__ slen,
                       float* __restrict__ out) {
  const int m = blockIdx.x;
  const int c = threadIdx.x;
  const int s = sstart[m];
  const int L = slen[m];
  float sum = 0.f;
  for (int i = 0; i < L; ++i) sum += atomh[(size_t)(s + i) * H + c];
  out[m * H + c] = sum / (float)L;
}

extern "C" void kernel_launch(void* const* d_in, const int* in_sizes, int n_in,
                              void* d_out, int out_size, void* d_ws, size_t ws_size,
                              hipStream_t stream) {
  const float* fatoms = (const float*)d_in[0];
  const float* fbonds = (const float*)d_in[1];
  const int* agraph = (const int*)d_in[2];
  const int* bgraph = (const int*)d_in[3];
  const int* sstart = (const int*)d_in[4];
  const int* slen = (const int*)d_in[5];
  const float* Wi = (const float*)d_in[6];
  const float* Wh = (const float*)d_in[7];
  const float* Wo = (const float*)d_in[8];
  const float* bo = (const float*)d_in[9];
  float* out = (float*)d_out;

  const size_t EH = (size_t)EDGES * H;
  bf16s* binput = (bf16s*)d_ws;          // [E,H] bf16, 51.2 MB
  bf16s* message = binput + EH;          // [E,H] bf16
  bf16s* msgW = message + EH;            // [E,H] bf16
  float* atomh = (float*)d_ws;           // overlays binput (dead after last gather)
  bf16s* wt_h = (bf16s*)d_out;           // stashed in d_out; k_pool overwrites later
  bf16s* wt_o = wt_h + H * H;

  k_wt<<<2, 256, 0, stream>>>(Wh, Wo, wt_h, wt_o);
  k_binput<<<EDGES / 8, 256, 0, stream>>>(fbonds, Wi, binput, message);
  for (int d = 0; d < 5; ++d) {
    k_gemm_mfma<<<EDGES / 64, 256, 0, stream>>>(message, wt_h, msgW);
    k_gather_relu<<<EDGES / 8, 256, 0, stream>>>(bgraph, msgW, binput, message);
  }
  k_gemm_mfma<<<EDGES / 64, 256, 0, stream>>>(message, wt_o, msgW);
  k_atoms<<<NATOMS / 8, 256, 0, stream>>>(fatoms, agraph, msgW, Wo, bo, atomh);
  k_pool<<<NMOLS, H, 0, stream>>>(atomh, sstart, slen, out);
}